// Round 2
// baseline (831.150 us; speedup 1.0000x reference)
//
#include <hip/hip_runtime.h>
#include <hip/hip_bf16.h>

// ---------------- utility kernels ----------------

__global__ void k_zero_int(int* __restrict__ p, int n) {
  int i = blockIdx.x * blockDim.x + threadIdx.x;
  if (i < n) p[i] = 0;
}

__global__ void k_hist(const int* __restrict__ dst, int* __restrict__ cnt, int nE) {
  int e = blockIdx.x * blockDim.x + threadIdx.x;
  if (e < nE) atomicAdd(&cnt[dst[e]], 1);
}

__global__ void k_dinv(const int* __restrict__ cnt, float* __restrict__ dinv, int n) {
  int i = blockIdx.x * blockDim.x + threadIdx.x;
  if (i < n) dinv[i] = rsqrtf((float)(cnt[i] + 1));  // +1 self-loop
}

// ---- 3-phase exclusive scan of cnt[N] -> rowptr[N] (and cursor copy) ----

__global__ void k_blocksum(const int* __restrict__ cnt, int* __restrict__ bsum, int n) {
  __shared__ int red[256];
  int tid = threadIdx.x;
  int base = blockIdx.x * 1024 + tid * 4;
  int s = 0;
#pragma unroll
  for (int i = 0; i < 4; i++) { int idx = base + i; if (idx < n) s += cnt[idx]; }
  red[tid] = s;
  __syncthreads();
  for (int off = 128; off > 0; off >>= 1) {
    if (tid < off) red[tid] += red[tid + off];
    __syncthreads();
  }
  if (tid == 0) bsum[blockIdx.x] = red[0];
}

__global__ void k_scan_bsum(int* __restrict__ bsum, int nb) {
  __shared__ int s[128];
  int tid = threadIdx.x;
  int v = (tid < nb) ? bsum[tid] : 0;
  s[tid] = v;
  __syncthreads();
  for (int off = 1; off < 128; off <<= 1) {
    int t = (tid >= off) ? s[tid - off] : 0;
    __syncthreads();
    s[tid] += t;
    __syncthreads();
  }
  if (tid < nb) bsum[tid] = s[tid] - v;  // exclusive
}

__global__ void k_scan_final(const int* __restrict__ cnt, const int* __restrict__ bsum,
                             int* __restrict__ rowptr, int* __restrict__ cursor, int n) {
  __shared__ int tsum[256];
  int tid = threadIdx.x;
  int base = blockIdx.x * 1024 + tid * 4;
  int v[4]; int s = 0;
#pragma unroll
  for (int i = 0; i < 4; i++) { v[i] = (base + i < n) ? cnt[base + i] : 0; s += v[i]; }
  tsum[tid] = s;
  __syncthreads();
  for (int off = 1; off < 256; off <<= 1) {
    int t = (tid >= off) ? tsum[tid - off] : 0;
    __syncthreads();
    tsum[tid] += t;
    __syncthreads();
  }
  int run = bsum[blockIdx.x] + tsum[tid] - s;  // exclusive prefix at first elem
#pragma unroll
  for (int i = 0; i < 4; i++) {
    int idx = base + i;
    if (idx < n) { rowptr[idx] = run; cursor[idx] = run; run += v[i]; }
  }
}

__global__ void k_place(const int* __restrict__ src, const int* __restrict__ dst,
                        const float* __restrict__ dinv, int* __restrict__ cursor,
                        int* __restrict__ col, float* __restrict__ ew, int nE) {
  int e = blockIdx.x * blockDim.x + threadIdx.x;
  if (e < nE) {
    int s = src[e], d = dst[e];
    int pos = atomicAdd(&cursor[d], 1);
    col[pos] = s;
    ew[pos] = dinv[s] * dinv[d];
  }
}

// ---------------- tiled f32 GEMM: out[M,128] = A[M,K] @ W[K,128] (+bias) ----------------
// BM=64, BN=128, BK=32, 256 threads, 8x4 micro-tile per thread.

__global__ __launch_bounds__(256) void k_gemm_n128(
    const float* __restrict__ A, const float* __restrict__ W,
    const float* __restrict__ bias, float* __restrict__ out,
    int M, int K, int use_bias) {
  __shared__ float As[64 * 32];
  __shared__ float Ws[32 * 128];
  int tid = threadIdx.x;
  int tcol = tid & 31;   // cols 4*tcol .. +3
  int trow = tid >> 5;   // rows 8*trow .. +7
  int row0 = blockIdx.x * 64;

  float acc[8][4];
#pragma unroll
  for (int i = 0; i < 8; i++)
#pragma unroll
    for (int j = 0; j < 4; j++) acc[i][j] = 0.f;

  int ar = tid >> 2;            // 0..63
  int ac = (tid & 3) * 8;       // 0,8,16,24
  int wr = tid >> 3;            // 0..31
  int wc = (tid & 7) * 16;      // 0..112

  for (int k0 = 0; k0 < K; k0 += 32) {
    if (row0 + ar < M) {
      const float* s = A + (size_t)(row0 + ar) * K + k0 + ac;
      float4 v0 = *(const float4*)s;
      float4 v1 = *(const float4*)(s + 4);
      *(float4*)&As[ar * 32 + ac] = v0;
      *(float4*)&As[ar * 32 + ac + 4] = v1;
    }
    {
      const float* s = W + (size_t)(k0 + wr) * 128 + wc;
      float4 w0 = *(const float4*)s;
      float4 w1 = *(const float4*)(s + 4);
      float4 w2 = *(const float4*)(s + 8);
      float4 w3 = *(const float4*)(s + 12);
      *(float4*)&Ws[wr * 128 + wc] = w0;
      *(float4*)&Ws[wr * 128 + wc + 4] = w1;
      *(float4*)&Ws[wr * 128 + wc + 8] = w2;
      *(float4*)&Ws[wr * 128 + wc + 12] = w3;
    }
    __syncthreads();
#pragma unroll
    for (int k = 0; k < 32; k += 4) {
      float4 b0 = *(const float4*)&Ws[(k + 0) * 128 + tcol * 4];
      float4 b1 = *(const float4*)&Ws[(k + 1) * 128 + tcol * 4];
      float4 b2 = *(const float4*)&Ws[(k + 2) * 128 + tcol * 4];
      float4 b3 = *(const float4*)&Ws[(k + 3) * 128 + tcol * 4];
#pragma unroll
      for (int i = 0; i < 8; i++) {
        float4 a = *(const float4*)&As[(trow * 8 + i) * 32 + k];
        acc[i][0] += a.x * b0.x + a.y * b1.x + a.z * b2.x + a.w * b3.x;
        acc[i][1] += a.x * b0.y + a.y * b1.y + a.z * b2.y + a.w * b3.y;
        acc[i][2] += a.x * b0.z + a.y * b1.z + a.z * b2.z + a.w * b3.z;
        acc[i][3] += a.x * b0.w + a.y * b1.w + a.z * b2.w + a.w * b3.w;
      }
    }
    __syncthreads();
  }

  float4 bb = make_float4(0.f, 0.f, 0.f, 0.f);
  if (use_bias) bb = *(const float4*)&bias[tcol * 4];
#pragma unroll
  for (int i = 0; i < 8; i++) {
    int r = row0 + trow * 8 + i;
    if (r < M) {
      float4 o;
      o.x = acc[i][0] + bb.x;
      o.y = acc[i][1] + bb.y;
      o.z = acc[i][2] + bb.z;
      o.w = acc[i][3] + bb.w;
      *(float4*)&out[(size_t)r * 128 + tcol * 4] = o;
    }
  }
}

// ---------------- pull-based SpMM: out[n] = dinv[n]^2*in[n] + sum_e ew*in[col] (+bias, relu) ----------------
// one 64-lane wave per node, float2 per lane (128 channels).

__global__ __launch_bounds__(256) void k_spmm(
    const float* __restrict__ in, const int* __restrict__ rowptr,
    const int* __restrict__ cnt, const int* __restrict__ col,
    const float* __restrict__ ew, const float* __restrict__ dinv,
    const float* __restrict__ bias, float* __restrict__ out,
    int n, int use_bias, int relu_out) {
  int node = blockIdx.x * 4 + (threadIdx.x >> 6);
  if (node >= n) return;
  int lane = threadIdx.x & 63;

  float di = dinv[node];
  float w0 = di * di;
  float2 v = ((const float2*)(in + (size_t)node * 128))[lane];
  float2 acc;
  acc.x = w0 * v.x;
  acc.y = w0 * v.y;

  int beg = rowptr[node];
  int m = cnt[node];
  int i = 0;
  for (; i + 2 <= m; i += 2) {
    int c0 = col[beg + i], c1 = col[beg + i + 1];
    float e0 = ew[beg + i], e1 = ew[beg + i + 1];
    float2 u0 = ((const float2*)(in + (size_t)c0 * 128))[lane];
    float2 u1 = ((const float2*)(in + (size_t)c1 * 128))[lane];
    acc.x += e0 * u0.x + e1 * u1.x;
    acc.y += e0 * u0.y + e1 * u1.y;
  }
  if (i < m) {
    int c0 = col[beg + i];
    float e0 = ew[beg + i];
    float2 u0 = ((const float2*)(in + (size_t)c0 * 128))[lane];
    acc.x += e0 * u0.x;
    acc.y += e0 * u0.y;
  }
  if (use_bias) {
    acc.x += bias[2 * lane];
    acc.y += bias[2 * lane + 1];
  }
  if (relu_out) {
    acc.x = fmaxf(acc.x, 0.f);
    acc.y = fmaxf(acc.y, 0.f);
  }
  ((float2*)(out + (size_t)node * 128))[lane] = acc;
}

// ---------------- launch ----------------

extern "C" void kernel_launch(void* const* d_in, const int* in_sizes, int n_in,
                              void* d_out, int out_size, void* d_ws, size_t ws_size,
                              hipStream_t stream) {
  const float* x   = (const float*)d_in[0];
  const int*   ei  = (const int*)d_in[1];   // harness passes integers as int32
  const float* W1  = (const float*)d_in[2];
  const float* b1  = (const float*)d_in[3];
  const float* Wmu = (const float*)d_in[4];
  const float* bmu = (const float*)d_in[5];
  const float* Wls = (const float*)d_in[6];
  const float* bls = (const float*)d_in[7];

  int N = in_sizes[0] / 256;
  int E = in_sizes[1] / 2;
  const int* src = ei;
  const int* dst = ei + E;

  char* ws = (char*)d_ws;
  size_t o = 0;
  auto alloc = [&](size_t b) { size_t c = o; o = (o + b + 511) & ~(size_t)511; return c; };
  int*   cnt    = (int*)(ws + alloc((size_t)N * 4));
  int*   rowptr = (int*)(ws + alloc((size_t)N * 4));
  int*   cursor = (int*)(ws + alloc((size_t)N * 4));
  int*   bsum   = (int*)(ws + alloc(512));
  float* dinv   = (float*)(ws + alloc((size_t)N * 4));
  int*   col    = (int*)(ws + alloc((size_t)E * 4));
  float* ewt    = (float*)(ws + alloc((size_t)E * 4));
  float* bufA   = (float*)(ws + alloc((size_t)N * 128 * 4));  // h0, later g

  float* outMu = (float*)d_out;
  float* outLs = outMu + (size_t)N * 128;
  float* hBuf  = outMu;  // stage h in mu-region; overwritten by final GEMM

  int nbScan = (N + 1023) / 1024;

  k_zero_int<<<(N + 255) / 256, 256, 0, stream>>>(cnt, N);
  k_hist<<<(E + 255) / 256, 256, 0, stream>>>(dst, cnt, E);
  k_dinv<<<(N + 255) / 256, 256, 0, stream>>>(cnt, dinv, N);
  k_blocksum<<<nbScan, 256, 0, stream>>>(cnt, bsum, N);
  k_scan_bsum<<<1, 128, 0, stream>>>(bsum, nbScan);
  k_scan_final<<<nbScan, 256, 0, stream>>>(cnt, bsum, rowptr, cursor, N);
  k_place<<<(E + 255) / 256, 256, 0, stream>>>(src, dst, dinv, cursor, col, ewt, E);

  // h0 = x @ W1                 [N,128]  (bufA)
  k_gemm_n128<<<(N + 63) / 64, 256, 0, stream>>>(x, W1, nullptr, bufA, N, 256, 0);
  // h = relu(A h0 + b1)         [N,128]  (staged in outMu region)
  k_spmm<<<(N + 3) / 4, 256, 0, stream>>>(bufA, rowptr, cnt, col, ewt, dinv, b1, hBuf, N, 1, 1);
  // g = A h                     [N,128]  (back into bufA)
  k_spmm<<<(N + 3) / 4, 256, 0, stream>>>(hBuf, rowptr, cnt, col, ewt, dinv, nullptr, bufA, N, 0, 0);
  // mu = g @ Wmu + bmu ; ls = g @ Wls + bls
  k_gemm_n128<<<(N + 63) / 64, 256, 0, stream>>>(bufA, Wmu, bmu, outMu, N, 128, 1);
  k_gemm_n128<<<(N + 63) / 64, 256, 0, stream>>>(bufA, Wls, bls, outLs, N, 128, 1);
}

// Round 3
// 558.065 us; speedup vs baseline: 1.4893x; 1.4893x over previous
//
#include <hip/hip_runtime.h>
#include <hip/hip_bf16.h>

typedef __attribute__((ext_vector_type(8))) short bf16x8;
typedef __attribute__((ext_vector_type(4))) float f32x4;

__device__ __forceinline__ unsigned short bf16_rne(float f) {
  unsigned u = __builtin_bit_cast(unsigned, f);
  unsigned r = u + 0x7fffu + ((u >> 16) & 1u);
  return (unsigned short)(r >> 16);
}
__device__ __forceinline__ float bf16_to_f32(unsigned short h) {
  return __builtin_bit_cast(float, (unsigned)h << 16);
}

// ---------------- utility kernels ----------------

__global__ void k_zero_int(int* __restrict__ p, int n) {
  int i = blockIdx.x * blockDim.x + threadIdx.x;
  if (i < n) p[i] = 0;
}

__global__ void k_hist(const int* __restrict__ dst, int* __restrict__ cnt, int nE) {
  int e = blockIdx.x * blockDim.x + threadIdx.x;
  if (e < nE) atomicAdd(&cnt[dst[e]], 1);
}

__global__ void k_dinv(const int* __restrict__ cnt, float* __restrict__ dinv, int n) {
  int i = blockIdx.x * blockDim.x + threadIdx.x;
  if (i < n) dinv[i] = rsqrtf((float)(cnt[i] + 1));  // +1 self-loop
}

// ---- 3-phase exclusive scan of cnt[N] -> rowptr[N] (and cursor copy) ----

__global__ void k_blocksum(const int* __restrict__ cnt, int* __restrict__ bsum, int n) {
  __shared__ int red[256];
  int tid = threadIdx.x;
  int base = blockIdx.x * 1024 + tid * 4;
  int s = 0;
#pragma unroll
  for (int i = 0; i < 4; i++) { int idx = base + i; if (idx < n) s += cnt[idx]; }
  red[tid] = s;
  __syncthreads();
  for (int off = 128; off > 0; off >>= 1) {
    if (tid < off) red[tid] += red[tid + off];
    __syncthreads();
  }
  if (tid == 0) bsum[blockIdx.x] = red[0];
}

__global__ void k_scan_bsum(int* __restrict__ bsum, int nb) {
  __shared__ int s[128];
  int tid = threadIdx.x;
  int v = (tid < nb) ? bsum[tid] : 0;
  s[tid] = v;
  __syncthreads();
  for (int off = 1; off < 128; off <<= 1) {
    int t = (tid >= off) ? s[tid - off] : 0;
    __syncthreads();
    s[tid] += t;
    __syncthreads();
  }
  if (tid < nb) bsum[tid] = s[tid] - v;  // exclusive
}

__global__ void k_scan_final(const int* __restrict__ cnt, const int* __restrict__ bsum,
                             int* __restrict__ rowptr, int* __restrict__ cursor, int n) {
  __shared__ int tsum[256];
  int tid = threadIdx.x;
  int base = blockIdx.x * 1024 + tid * 4;
  int v[4]; int s = 0;
#pragma unroll
  for (int i = 0; i < 4; i++) { v[i] = (base + i < n) ? cnt[base + i] : 0; s += v[i]; }
  tsum[tid] = s;
  __syncthreads();
  for (int off = 1; off < 256; off <<= 1) {
    int t = (tid >= off) ? tsum[tid - off] : 0;
    __syncthreads();
    tsum[tid] += t;
    __syncthreads();
  }
  int run = bsum[blockIdx.x] + tsum[tid] - s;  // exclusive prefix at first elem
#pragma unroll
  for (int i = 0; i < 4; i++) {
    int idx = base + i;
    if (idx < n) { rowptr[idx] = run; cursor[idx] = run; run += v[i]; }
  }
}

__global__ void k_place(const int* __restrict__ src, const int* __restrict__ dst,
                        const float* __restrict__ dinv, int* __restrict__ cursor,
                        int* __restrict__ col, float* __restrict__ ew, int nE) {
  int e = blockIdx.x * blockDim.x + threadIdx.x;
  if (e < nE) {
    int s = src[e], d = dst[e];
    int pos = atomicAdd(&cursor[d], 1);
    col[pos] = s;
    ew[pos] = dinv[s] * dinv[d];
  }
}

// ---- weight prep: split-bf16 + transpose; fuse Wmu|Wls, bmu|bls ----
// W1T[n][k] n<128,k<256 from W1[k][n]; WcatT[n][k] n<256,k<128 from Wmu/Wls.

__global__ void k_prep_w(const float* __restrict__ W1,
                         const float* __restrict__ Wmu, const float* __restrict__ Wls,
                         const float* __restrict__ bmu, const float* __restrict__ bls,
                         unsigned short* __restrict__ W1Th, unsigned short* __restrict__ W1Tl,
                         unsigned short* __restrict__ WcTh, unsigned short* __restrict__ WcTl,
                         float* __restrict__ bcat) {
  int i = blockIdx.x * blockDim.x + threadIdx.x;
  if (i < 128 * 256) {                     // W1T
    int n = i >> 8, k = i & 255;
    float f = W1[k * 128 + n];
    unsigned short hi = bf16_rne(f);
    W1Th[i] = hi;
    W1Tl[i] = bf16_rne(f - bf16_to_f32(hi));
  } else if (i < 2 * 128 * 256) {          // WcatT
    int j = i - 128 * 256;
    int n = j >> 7, k = j & 127;
    float f = (n < 128) ? Wmu[k * 128 + n] : Wls[k * 128 + (n - 128)];
    unsigned short hi = bf16_rne(f);
    WcTh[j] = hi;
    WcTl[j] = bf16_rne(f - bf16_to_f32(hi));
  } else if (i < 2 * 128 * 256 + 256) {    // bcat
    int n = i - 2 * 128 * 256;
    bcat[n] = (n < 128) ? bmu[n] : bls[n - 128];
  }
}

// ---------------- MFMA GEMM: out[M, 128-per-blockcol] = A[M,K](f32) @ W[K,N] ----------------
// Split-precision: A = Ah+Al (bf16), W pre-split WTh/WTl transposed [N][K].
// acc = Ah*Wh + Ah*Wl + Al*Wh  (f32 MFMA accumulate) -> ~f32 accuracy.
// Block: 256 thr (4 waves 2x2), BM=128, BN=128, BK=32. mfma_f32_16x16x32_bf16.

#define LP 40  // LDS row stride in bf16 elems (32 + 8 pad, keeps 16B alignment)

__global__ __launch_bounds__(256) void k_gemm_mfma(
    const float* __restrict__ A,
    const unsigned short* __restrict__ WTh, const unsigned short* __restrict__ WTl,
    const float* __restrict__ bias, float* __restrict__ out0, float* __restrict__ out1,
    int M, int K, int split_out) {
  __shared__ unsigned short Ah[128 * LP];
  __shared__ unsigned short Al[128 * LP];
  __shared__ unsigned short Bh[128 * LP];
  __shared__ unsigned short Bl[128 * LP];

  const int tid = threadIdx.x;
  const int lane = tid & 63;
  const int wv = tid >> 6;
  const int wr = wv >> 1, wc = wv & 1;   // 2x2 waves, each 64x64
  const int rsel = lane >> 4;            // 0..3
  const int rrow = lane & 15;
  const int row0 = blockIdx.x * 128;
  const int col0 = blockIdx.y * 128;

  f32x4 acc[4][4];
#pragma unroll
  for (int m = 0; m < 4; m++)
#pragma unroll
    for (int n = 0; n < 4; n++) acc[m][n] = (f32x4){0.f, 0.f, 0.f, 0.f};

  const int srow = tid >> 1;            // staging row 0..127
  const int skh = (tid & 1) * 16;       // k-half 0 or 16

  for (int k0 = 0; k0 < K; k0 += 32) {
    // ---- stage A tile (f32 -> split bf16) ----
    {
      if (row0 + srow < M) {
        const float* src = A + (size_t)(row0 + srow) * K + k0 + skh;
#pragma unroll
        for (int half = 0; half < 2; half++) {
          float4 f0 = *(const float4*)(src + half * 8);
          float4 f1 = *(const float4*)(src + half * 8 + 4);
          bf16x8 vh, vl;
          float fv[8] = {f0.x, f0.y, f0.z, f0.w, f1.x, f1.y, f1.z, f1.w};
#pragma unroll
          for (int j = 0; j < 8; j++) {
            unsigned short hi = bf16_rne(fv[j]);
            vh[j] = (short)hi;
            vl[j] = (short)bf16_rne(fv[j] - bf16_to_f32(hi));
          }
          *(bf16x8*)&Ah[srow * LP + skh + half * 8] = vh;
          *(bf16x8*)&Al[srow * LP + skh + half * 8] = vl;
        }
      } else {
        bf16x8 z = (bf16x8){0,0,0,0,0,0,0,0};
        *(bf16x8*)&Ah[srow * LP + skh] = z; *(bf16x8*)&Ah[srow * LP + skh + 8] = z;
        *(bf16x8*)&Al[srow * LP + skh] = z; *(bf16x8*)&Al[srow * LP + skh + 8] = z;
      }
      // ---- stage W tile (already split bf16, transposed [N][K]) ----
      const unsigned short* sh = WTh + (size_t)(col0 + srow) * K + k0 + skh;
      const unsigned short* sl = WTl + (size_t)(col0 + srow) * K + k0 + skh;
      *(bf16x8*)&Bh[srow * LP + skh]     = *(const bf16x8*)sh;
      *(bf16x8*)&Bh[srow * LP + skh + 8] = *(const bf16x8*)(sh + 8);
      *(bf16x8*)&Bl[srow * LP + skh]     = *(const bf16x8*)sl;
      *(bf16x8*)&Bl[srow * LP + skh + 8] = *(const bf16x8*)(sl + 8);
    }
    __syncthreads();

    // ---- fragments + MFMA ----
    bf16x8 fah[4], fal[4], fbh[4], fbl[4];
#pragma unroll
    for (int m = 0; m < 4; m++) {
      int off = (wr * 64 + m * 16 + rrow) * LP + rsel * 8;
      fah[m] = *(bf16x8*)&Ah[off];
      fal[m] = *(bf16x8*)&Al[off];
    }
#pragma unroll
    for (int n = 0; n < 4; n++) {
      int off = (wc * 64 + n * 16 + rrow) * LP + rsel * 8;
      fbh[n] = *(bf16x8*)&Bh[off];
      fbl[n] = *(bf16x8*)&Bl[off];
    }
#pragma unroll
    for (int m = 0; m < 4; m++)
#pragma unroll
      for (int n = 0; n < 4; n++) {
        acc[m][n] = __builtin_amdgcn_mfma_f32_16x16x32_bf16(fah[m], fbh[n], acc[m][n], 0, 0, 0);
        acc[m][n] = __builtin_amdgcn_mfma_f32_16x16x32_bf16(fah[m], fbl[n], acc[m][n], 0, 0, 0);
        acc[m][n] = __builtin_amdgcn_mfma_f32_16x16x32_bf16(fal[m], fbh[n], acc[m][n], 0, 0, 0);
      }
    __syncthreads();
  }

  // ---- epilogue: D col=lane&15, row=4*(lane>>4)+reg ----
#pragma unroll
  for (int n = 0; n < 4; n++) {
    int col = col0 + wc * 64 + n * 16 + rrow;
    float badd = bias ? bias[col] : 0.f;
    float* dstBase = out0;
    int c = col;
    if (split_out && c >= 128) { dstBase = out1; c -= 128; }
#pragma unroll
    for (int m = 0; m < 4; m++) {
      f32x4 v = acc[m][n];
#pragma unroll
      for (int r = 0; r < 4; r++) {
        int row = row0 + wr * 64 + m * 16 + rsel * 4 + r;
        if (row < M) dstBase[(size_t)row * 128 + c] = v[r] + badd;
      }
    }
  }
}

// ---------------- pull-based SpMM: out[n] = dinv[n]^2*in[n] + sum_e ew*in[col] (+bias, relu) ----------------

__global__ __launch_bounds__(256) void k_spmm(
    const float* __restrict__ in, const int* __restrict__ rowptr,
    const int* __restrict__ cnt, const int* __restrict__ col,
    const float* __restrict__ ew, const float* __restrict__ dinv,
    const float* __restrict__ bias, float* __restrict__ out,
    int n, int use_bias, int relu_out) {
  int node = blockIdx.x * 4 + (threadIdx.x >> 6);
  if (node >= n) return;
  int lane = threadIdx.x & 63;

  float di = dinv[node];
  float w0 = di * di;
  float2 v = ((const float2*)(in + (size_t)node * 128))[lane];
  float2 acc;
  acc.x = w0 * v.x;
  acc.y = w0 * v.y;

  int beg = rowptr[node];
  int m = cnt[node];
  int i = 0;
  for (; i + 2 <= m; i += 2) {
    int c0 = col[beg + i], c1 = col[beg + i + 1];
    float e0 = ew[beg + i], e1 = ew[beg + i + 1];
    float2 u0 = ((const float2*)(in + (size_t)c0 * 128))[lane];
    float2 u1 = ((const float2*)(in + (size_t)c1 * 128))[lane];
    acc.x += e0 * u0.x + e1 * u1.x;
    acc.y += e0 * u0.y + e1 * u1.y;
  }
  if (i < m) {
    int c0 = col[beg + i];
    float e0 = ew[beg + i];
    float2 u0 = ((const float2*)(in + (size_t)c0 * 128))[lane];
    acc.x += e0 * u0.x;
    acc.y += e0 * u0.y;
  }
  if (use_bias) {
    acc.x += bias[2 * lane];
    acc.y += bias[2 * lane + 1];
  }
  if (relu_out) {
    acc.x = fmaxf(acc.x, 0.f);
    acc.y = fmaxf(acc.y, 0.f);
  }
  ((float2*)(out + (size_t)node * 128))[lane] = acc;
}

// ---------------- launch ----------------

extern "C" void kernel_launch(void* const* d_in, const int* in_sizes, int n_in,
                              void* d_out, int out_size, void* d_ws, size_t ws_size,
                              hipStream_t stream) {
  const float* x   = (const float*)d_in[0];
  const int*   ei  = (const int*)d_in[1];
  const float* W1  = (const float*)d_in[2];
  const float* b1  = (const float*)d_in[3];
  const float* Wmu = (const float*)d_in[4];
  const float* bmu = (const float*)d_in[5];
  const float* Wls = (const float*)d_in[6];
  const float* bls = (const float*)d_in[7];

  int N = in_sizes[0] / 256;
  int E = in_sizes[1] / 2;
  const int* src = ei;
  const int* dst = ei + E;

  char* ws = (char*)d_ws;
  size_t o = 0;
  auto alloc = [&](size_t b) { size_t c = o; o = (o + b + 511) & ~(size_t)511; return c; };
  int*   cnt    = (int*)(ws + alloc((size_t)N * 4));
  int*   rowptr = (int*)(ws + alloc((size_t)N * 4));
  int*   cursor = (int*)(ws + alloc((size_t)N * 4));
  int*   bsum   = (int*)(ws + alloc(512));
  float* dinv   = (float*)(ws + alloc((size_t)N * 4));
  int*   col    = (int*)(ws + alloc((size_t)E * 4));
  float* ewt    = (float*)(ws + alloc((size_t)E * 4));
  unsigned short* W1Th = (unsigned short*)(ws + alloc(128 * 256 * 2));
  unsigned short* W1Tl = (unsigned short*)(ws + alloc(128 * 256 * 2));
  unsigned short* WcTh = (unsigned short*)(ws + alloc(256 * 128 * 2));
  unsigned short* WcTl = (unsigned short*)(ws + alloc(256 * 128 * 2));
  float* bcat  = (float*)(ws + alloc(256 * 4));
  float* bufA  = (float*)(ws + alloc((size_t)N * 128 * 4));  // h0, later g

  float* outMu = (float*)d_out;
  float* outLs = outMu + (size_t)N * 128;
  float* hBuf  = outMu;  // stage h in mu-region; overwritten by final GEMM

  int nbScan = (N + 1023) / 1024;

  k_zero_int<<<(N + 255) / 256, 256, 0, stream>>>(cnt, N);
  k_hist<<<(E + 255) / 256, 256, 0, stream>>>(dst, cnt, E);
  k_dinv<<<(N + 255) / 256, 256, 0, stream>>>(cnt, dinv, N);
  k_blocksum<<<nbScan, 256, 0, stream>>>(cnt, bsum, N);
  k_scan_bsum<<<1, 128, 0, stream>>>(bsum, nbScan);
  k_scan_final<<<nbScan, 256, 0, stream>>>(cnt, bsum, rowptr, cursor, N);
  k_place<<<(E + 255) / 256, 256, 0, stream>>>(src, dst, dinv, cursor, col, ewt, E);
  k_prep_w<<<(2 * 128 * 256 + 256 + 255) / 256, 256, 0, stream>>>(
      W1, Wmu, Wls, bmu, bls, W1Th, W1Tl, WcTh, WcTl, bcat);

  int gx = (N + 127) / 128;
  // h0 = x @ W1                 [N,128]  (bufA)
  k_gemm_mfma<<<dim3(gx, 1), 256, 0, stream>>>(x, W1Th, W1Tl, nullptr, bufA, nullptr, N, 256, 0);
  // h = relu(A h0 + b1)         [N,128]  (staged in outMu region)
  k_spmm<<<(N + 3) / 4, 256, 0, stream>>>(bufA, rowptr, cnt, col, ewt, dinv, b1, hBuf, N, 1, 1);
  // g = A h                     [N,128]  (back into bufA)
  k_spmm<<<(N + 3) / 4, 256, 0, stream>>>(hBuf, rowptr, cnt, col, ewt, dinv, nullptr, bufA, N, 0, 0);
  // [mu | ls] = g @ [Wmu|Wls] + [bmu|bls]   one fused dispatch, grid.y=2
  k_gemm_mfma<<<dim3(gx, 2), 256, 0, stream>>>(bufA, WcTh, WcTl, bcat, outMu, outLs, N, 128, 1);
}

// Round 4
// 447.669 us; speedup vs baseline: 1.8566x; 1.2466x over previous
//
#include <hip/hip_runtime.h>
#include <hip/hip_bf16.h>
#include <hip/hip_fp16.h>

typedef __attribute__((ext_vector_type(8))) short bf16x8;
typedef __attribute__((ext_vector_type(8))) short short8;
typedef __attribute__((ext_vector_type(4))) float f32x4;

__device__ __forceinline__ unsigned short bf16_rne(float f) {
  unsigned u = __builtin_bit_cast(unsigned, f);
  unsigned r = u + 0x7fffu + ((u >> 16) & 1u);
  return (unsigned short)(r >> 16);
}
__device__ __forceinline__ float bf16_to_f32(unsigned short h) {
  return __builtin_bit_cast(float, (unsigned)h << 16);
}

// ---------------- utility kernels ----------------

__global__ void k_zero_int(int* __restrict__ p, int n) {
  int i = blockIdx.x * blockDim.x + threadIdx.x;
  if (i < n) p[i] = 0;
}

__global__ void k_hist(const int* __restrict__ dst, int* __restrict__ cnt, int nE) {
  int e = blockIdx.x * blockDim.x + threadIdx.x;
  if (e < nE) atomicAdd(&cnt[dst[e]], 1);
}

__global__ void k_dinv(const int* __restrict__ cnt, float* __restrict__ dinv, int n) {
  int i = blockIdx.x * blockDim.x + threadIdx.x;
  if (i < n) dinv[i] = rsqrtf((float)(cnt[i] + 1));  // +1 self-loop
}

// ---- 3-phase exclusive scan of cnt[N] -> rowptr[N] (and cursor copy) ----

__global__ void k_blocksum(const int* __restrict__ cnt, int* __restrict__ bsum, int n) {
  __shared__ int red[256];
  int tid = threadIdx.x;
  int base = blockIdx.x * 1024 + tid * 4;
  int s = 0;
#pragma unroll
  for (int i = 0; i < 4; i++) { int idx = base + i; if (idx < n) s += cnt[idx]; }
  red[tid] = s;
  __syncthreads();
  for (int off = 128; off > 0; off >>= 1) {
    if (tid < off) red[tid] += red[tid + off];
    __syncthreads();
  }
  if (tid == 0) bsum[blockIdx.x] = red[0];
}

__global__ void k_scan_bsum(int* __restrict__ bsum, int nb) {
  __shared__ int s[128];
  int tid = threadIdx.x;
  int v = (tid < nb) ? bsum[tid] : 0;
  s[tid] = v;
  __syncthreads();
  for (int off = 1; off < 128; off <<= 1) {
    int t = (tid >= off) ? s[tid - off] : 0;
    __syncthreads();
    s[tid] += t;
    __syncthreads();
  }
  if (tid < nb) bsum[tid] = s[tid] - v;  // exclusive
}

__global__ void k_scan_final(const int* __restrict__ cnt, const int* __restrict__ bsum,
                             int* __restrict__ rowptr, int* __restrict__ cursor, int n) {
  __shared__ int tsum[256];
  int tid = threadIdx.x;
  int base = blockIdx.x * 1024 + tid * 4;
  int v[4]; int s = 0;
#pragma unroll
  for (int i = 0; i < 4; i++) { v[i] = (base + i < n) ? cnt[base + i] : 0; s += v[i]; }
  tsum[tid] = s;
  __syncthreads();
  for (int off = 1; off < 256; off <<= 1) {
    int t = (tid >= off) ? tsum[tid - off] : 0;
    __syncthreads();
    tsum[tid] += t;
    __syncthreads();
  }
  int run = bsum[blockIdx.x] + tsum[tid] - s;  // exclusive prefix at first elem
#pragma unroll
  for (int i = 0; i < 4; i++) {
    int idx = base + i;
    if (idx < n) { rowptr[idx] = run; cursor[idx] = run; run += v[i]; }
  }
}

__global__ void k_place(const int* __restrict__ src, const int* __restrict__ dst,
                        const float* __restrict__ dinv, int* __restrict__ cursor,
                        int* __restrict__ col, float* __restrict__ ew, int nE) {
  int e = blockIdx.x * blockDim.x + threadIdx.x;
  if (e < nE) {
    int s = src[e], d = dst[e];
    int pos = atomicAdd(&cursor[d], 1);
    col[pos] = s;
    ew[pos] = dinv[s] * dinv[d];
  }
}

// ---- weight prep: split-bf16 + transpose; fuse Wmu|Wls, bmu|bls ----

__global__ void k_prep_w(const float* __restrict__ W1,
                         const float* __restrict__ Wmu, const float* __restrict__ Wls,
                         const float* __restrict__ bmu, const float* __restrict__ bls,
                         unsigned short* __restrict__ W1Th, unsigned short* __restrict__ W1Tl,
                         unsigned short* __restrict__ WcTh, unsigned short* __restrict__ WcTl,
                         float* __restrict__ bcat) {
  int i = blockIdx.x * blockDim.x + threadIdx.x;
  if (i < 128 * 256) {                     // W1T [n][k]
    int n = i >> 8, k = i & 255;
    float f = W1[k * 128 + n];
    unsigned short hi = bf16_rne(f);
    W1Th[i] = hi;
    W1Tl[i] = bf16_rne(f - bf16_to_f32(hi));
  } else if (i < 2 * 128 * 256) {          // WcatT [n][k]
    int j = i - 128 * 256;
    int n = j >> 7, k = j & 127;
    float f = (n < 128) ? Wmu[k * 128 + n] : Wls[k * 128 + (n - 128)];
    unsigned short hi = bf16_rne(f);
    WcTh[j] = hi;
    WcTl[j] = bf16_rne(f - bf16_to_f32(hi));
  } else if (i < 2 * 128 * 256 + 256) {    // bcat
    int n = i - 2 * 128 * 256;
    bcat[n] = (n < 128) ? bmu[n] : bls[n - 128];
  }
}

// ---------------- MFMA GEMM ----------------
// Split-precision: A = Ah+Al (bf16), W pre-split WTh/WTl transposed [N][K].
// acc = Ah*Wh + Ah*Wl + Al*Wh. AFMT: 0=f32 A, 1=fp16 A. OFMT: 0=f32 out (+bias, split), 1=fp16 out.

#define LP 40  // LDS row stride in bf16 elems

template <int AFMT, int OFMT>
__global__ __launch_bounds__(256) void k_gemm_mfma(
    const void* __restrict__ Av,
    const unsigned short* __restrict__ WTh, const unsigned short* __restrict__ WTl,
    const float* __restrict__ bias, void* __restrict__ out0, void* __restrict__ out1,
    int M, int K, int split_out) {
  __shared__ unsigned short Ah[128 * LP];
  __shared__ unsigned short Al[128 * LP];
  __shared__ unsigned short Bh[128 * LP];
  __shared__ unsigned short Bl[128 * LP];

  const int tid = threadIdx.x;
  const int lane = tid & 63;
  const int wv = tid >> 6;
  const int wr = wv >> 1, wc = wv & 1;   // 2x2 waves, each 64x64
  const int rsel = lane >> 4;            // 0..3
  const int rrow = lane & 15;
  const int row0 = blockIdx.x * 128;
  const int col0 = blockIdx.y * 128;

  f32x4 acc[4][4];
#pragma unroll
  for (int m = 0; m < 4; m++)
#pragma unroll
    for (int n = 0; n < 4; n++) acc[m][n] = (f32x4){0.f, 0.f, 0.f, 0.f};

  const int srow = tid >> 1;            // staging row 0..127
  const int skh = (tid & 1) * 16;       // k-half 0 or 16

  for (int k0 = 0; k0 < K; k0 += 32) {
    // ---- stage A tile -> split bf16 ----
    if (row0 + srow < M) {
      float fv[16];
      if (AFMT == 0) {
        const float* src = (const float*)Av + (size_t)(row0 + srow) * K + k0 + skh;
        float4 f0 = *(const float4*)(src);
        float4 f1 = *(const float4*)(src + 4);
        float4 f2 = *(const float4*)(src + 8);
        float4 f3 = *(const float4*)(src + 12);
        fv[0]=f0.x; fv[1]=f0.y; fv[2]=f0.z; fv[3]=f0.w;
        fv[4]=f1.x; fv[5]=f1.y; fv[6]=f1.z; fv[7]=f1.w;
        fv[8]=f2.x; fv[9]=f2.y; fv[10]=f2.z; fv[11]=f2.w;
        fv[12]=f3.x; fv[13]=f3.y; fv[14]=f3.z; fv[15]=f3.w;
      } else {
        const __half* src = (const __half*)Av + (size_t)(row0 + srow) * K + k0 + skh;
        short8 r0 = *(const short8*)(src);
        short8 r1 = *(const short8*)(src + 8);
#pragma unroll
        for (int j = 0; j < 8; j++) {
          fv[j]     = __half2float(__builtin_bit_cast(__half, (unsigned short)r0[j]));
          fv[8 + j] = __half2float(__builtin_bit_cast(__half, (unsigned short)r1[j]));
        }
      }
      bf16x8 vh0, vl0, vh1, vl1;
#pragma unroll
      for (int j = 0; j < 8; j++) {
        unsigned short hi = bf16_rne(fv[j]);
        vh0[j] = (short)hi;
        vl0[j] = (short)bf16_rne(fv[j] - bf16_to_f32(hi));
        unsigned short hi2 = bf16_rne(fv[8 + j]);
        vh1[j] = (short)hi2;
        vl1[j] = (short)bf16_rne(fv[8 + j] - bf16_to_f32(hi2));
      }
      *(bf16x8*)&Ah[srow * LP + skh]     = vh0;
      *(bf16x8*)&Ah[srow * LP + skh + 8] = vh1;
      *(bf16x8*)&Al[srow * LP + skh]     = vl0;
      *(bf16x8*)&Al[srow * LP + skh + 8] = vl1;
    } else {
      bf16x8 z = (bf16x8){0,0,0,0,0,0,0,0};
      *(bf16x8*)&Ah[srow * LP + skh] = z; *(bf16x8*)&Ah[srow * LP + skh + 8] = z;
      *(bf16x8*)&Al[srow * LP + skh] = z; *(bf16x8*)&Al[srow * LP + skh + 8] = z;
    }
    // ---- stage W tile ----
    {
      const unsigned short* sh = WTh + (size_t)(col0 + srow) * K + k0 + skh;
      const unsigned short* sl = WTl + (size_t)(col0 + srow) * K + k0 + skh;
      *(bf16x8*)&Bh[srow * LP + skh]     = *(const bf16x8*)sh;
      *(bf16x8*)&Bh[srow * LP + skh + 8] = *(const bf16x8*)(sh + 8);
      *(bf16x8*)&Bl[srow * LP + skh]     = *(const bf16x8*)sl;
      *(bf16x8*)&Bl[srow * LP + skh + 8] = *(const bf16x8*)(sl + 8);
    }
    __syncthreads();

    bf16x8 fah[4], fal[4], fbh[4], fbl[4];
#pragma unroll
    for (int m = 0; m < 4; m++) {
      int off = (wr * 64 + m * 16 + rrow) * LP + rsel * 8;
      fah[m] = *(bf16x8*)&Ah[off];
      fal[m] = *(bf16x8*)&Al[off];
    }
#pragma unroll
    for (int n = 0; n < 4; n++) {
      int off = (wc * 64 + n * 16 + rrow) * LP + rsel * 8;
      fbh[n] = *(bf16x8*)&Bh[off];
      fbl[n] = *(bf16x8*)&Bl[off];
    }
#pragma unroll
    for (int m = 0; m < 4; m++)
#pragma unroll
      for (int n = 0; n < 4; n++) {
        acc[m][n] = __builtin_amdgcn_mfma_f32_16x16x32_bf16(fah[m], fbh[n], acc[m][n], 0, 0, 0);
        acc[m][n] = __builtin_amdgcn_mfma_f32_16x16x32_bf16(fah[m], fbl[n], acc[m][n], 0, 0, 0);
        acc[m][n] = __builtin_amdgcn_mfma_f32_16x16x32_bf16(fal[m], fbh[n], acc[m][n], 0, 0, 0);
      }
    __syncthreads();
  }

  // ---- epilogue: D col=lane&15, row=4*(lane>>4)+reg ----
#pragma unroll
  for (int n = 0; n < 4; n++) {
    int col = col0 + wc * 64 + n * 16 + rrow;
    float badd = bias ? bias[col] : 0.f;
    void* dstBase = out0;
    int c = col;
    if (split_out && c >= 128) { dstBase = out1; c -= 128; }
#pragma unroll
    for (int m = 0; m < 4; m++) {
      f32x4 v = acc[m][n];
#pragma unroll
      for (int r = 0; r < 4; r++) {
        int row = row0 + wr * 64 + m * 16 + rsel * 4 + r;
        if (row < M) {
          if (OFMT == 0)
            ((float*)dstBase)[(size_t)row * 128 + c] = v[r] + badd;
          else
            ((__half*)dstBase)[(size_t)row * 128 + c] = __float2half(v[r] + badd);
        }
      }
    }
  }
}

// ---------------- pull-based SpMM (fp16 rows): one wave per node ----------------

__global__ __launch_bounds__(256) void k_spmm_h(
    const __half* __restrict__ in, const int* __restrict__ rowptr,
    const int* __restrict__ cnt, const int* __restrict__ col,
    const float* __restrict__ ew, const float* __restrict__ dinv,
    const float* __restrict__ bias, __half* __restrict__ out,
    int n, int use_bias, int relu_out) {
  int node = blockIdx.x * 4 + (threadIdx.x >> 6);
  if (node >= n) return;
  int lane = threadIdx.x & 63;

  float di = dinv[node];
  float w0 = di * di;
  float2 v = __half22float2(((const __half2*)(in + (size_t)node * 128))[lane]);
  float accx = w0 * v.x;
  float accy = w0 * v.y;

  int beg = rowptr[node];
  int m = cnt[node];
  int i = 0;
  for (; i + 4 <= m; i += 4) {
    int c0 = col[beg + i], c1 = col[beg + i + 1], c2 = col[beg + i + 2], c3 = col[beg + i + 3];
    float e0 = ew[beg + i], e1 = ew[beg + i + 1], e2 = ew[beg + i + 2], e3 = ew[beg + i + 3];
    float2 u0 = __half22float2(((const __half2*)(in + (size_t)c0 * 128))[lane]);
    float2 u1 = __half22float2(((const __half2*)(in + (size_t)c1 * 128))[lane]);
    float2 u2 = __half22float2(((const __half2*)(in + (size_t)c2 * 128))[lane]);
    float2 u3 = __half22float2(((const __half2*)(in + (size_t)c3 * 128))[lane]);
    accx += e0 * u0.x + e1 * u1.x + e2 * u2.x + e3 * u3.x;
    accy += e0 * u0.y + e1 * u1.y + e2 * u2.y + e3 * u3.y;
  }
  for (; i < m; i++) {
    int c0 = col[beg + i];
    float e0 = ew[beg + i];
    float2 u0 = __half22float2(((const __half2*)(in + (size_t)c0 * 128))[lane]);
    accx += e0 * u0.x;
    accy += e0 * u0.y;
  }
  if (use_bias) {
    accx += bias[2 * lane];
    accy += bias[2 * lane + 1];
  }
  if (relu_out) {
    accx = fmaxf(accx, 0.f);
    accy = fmaxf(accy, 0.f);
  }
  ((__half2*)(out + (size_t)node * 128))[lane] = __floats2half2_rn(accx, accy);
}

// ---------------- launch ----------------

extern "C" void kernel_launch(void* const* d_in, const int* in_sizes, int n_in,
                              void* d_out, int out_size, void* d_ws, size_t ws_size,
                              hipStream_t stream) {
  const float* x   = (const float*)d_in[0];
  const int*   ei  = (const int*)d_in[1];
  const float* W1  = (const float*)d_in[2];
  const float* b1  = (const float*)d_in[3];
  const float* Wmu = (const float*)d_in[4];
  const float* bmu = (const float*)d_in[5];
  const float* Wls = (const float*)d_in[6];
  const float* bls = (const float*)d_in[7];

  int N = in_sizes[0] / 256;
  int E = in_sizes[1] / 2;
  const int* src = ei;
  const int* dst = ei + E;

  char* ws = (char*)d_ws;
  size_t o = 0;
  auto alloc = [&](size_t b) { size_t c = o; o = (o + b + 511) & ~(size_t)511; return c; };
  int*   cnt    = (int*)(ws + alloc((size_t)N * 4));
  int*   rowptr = (int*)(ws + alloc((size_t)N * 4));
  int*   cursor = (int*)(ws + alloc((size_t)N * 4));
  int*   bsum   = (int*)(ws + alloc(512));
  float* dinv   = (float*)(ws + alloc((size_t)N * 4));
  int*   col    = (int*)(ws + alloc((size_t)E * 4));
  float* ewt    = (float*)(ws + alloc((size_t)E * 4));
  unsigned short* W1Th = (unsigned short*)(ws + alloc(128 * 256 * 2));
  unsigned short* W1Tl = (unsigned short*)(ws + alloc(128 * 256 * 2));
  unsigned short* WcTh = (unsigned short*)(ws + alloc(256 * 128 * 2));
  unsigned short* WcTl = (unsigned short*)(ws + alloc(256 * 128 * 2));
  float*  bcat = (float*)(ws + alloc(256 * 4));
  __half* h0   = (__half*)(ws + alloc((size_t)N * 128 * 2));  // GEMM1 out, later g
  __half* hBuf = (__half*)(ws + alloc((size_t)N * 128 * 2));  // h (relu'd)

  float* outMu = (float*)d_out;
  float* outLs = outMu + (size_t)N * 128;

  int nbScan = (N + 1023) / 1024;

  k_zero_int<<<(N + 255) / 256, 256, 0, stream>>>(cnt, N);
  k_hist<<<(E + 255) / 256, 256, 0, stream>>>(dst, cnt, E);
  k_dinv<<<(N + 255) / 256, 256, 0, stream>>>(cnt, dinv, N);
  k_blocksum<<<nbScan, 256, 0, stream>>>(cnt, bsum, N);
  k_scan_bsum<<<1, 128, 0, stream>>>(bsum, nbScan);
  k_scan_final<<<nbScan, 256, 0, stream>>>(cnt, bsum, rowptr, cursor, N);
  k_place<<<(E + 255) / 256, 256, 0, stream>>>(src, dst, dinv, cursor, col, ewt, E);
  k_prep_w<<<(2 * 128 * 256 + 256 + 255) / 256, 256, 0, stream>>>(
      W1, Wmu, Wls, bmu, bls, W1Th, W1Tl, WcTh, WcTl, bcat);

  int gx = (N + 127) / 128;
  // h0 = x @ W1                 [N,128] fp16
  k_gemm_mfma<0, 1><<<dim3(gx, 1), 256, 0, stream>>>(x, W1Th, W1Tl, nullptr, h0, nullptr, N, 256, 0);
  // h = relu(A h0 + b1)         [N,128] fp16
  k_spmm_h<<<(N + 3) / 4, 256, 0, stream>>>(h0, rowptr, cnt, col, ewt, dinv, b1, hBuf, N, 1, 1);
  // g = A h                     [N,128] fp16 (reuse h0 buffer)
  k_spmm_h<<<(N + 3) / 4, 256, 0, stream>>>(hBuf, rowptr, cnt, col, ewt, dinv, nullptr, h0, N, 0, 0);
  // [mu | ls] = g @ [Wmu|Wls] + [bmu|bls]   one fused dispatch, grid.y=2
  k_gemm_mfma<1, 0><<<dim3(gx, 2), 256, 0, stream>>>(h0, WcTh, WcTl, bcat, outMu, outLs, N, 128, 1);
}